// Round 1
// baseline (448.400 us; speedup 1.0000x reference)
//
#include <hip/hip_runtime.h>
#include <hip/hip_bf16.h>
#include <math.h>

#define D 2048
#define H 256
#define E 16
#define TM 64          // tokens per block
#define BK 32          // k-chunk
#define LDW 36         // padded LDS row stride (floats): 4-float pad, 16B-aligned rows
#define THREADS 512
#define WS_STRIDE 20   // per-block partial: [0..15]=lb, [16]=z

__global__ __launch_bounds__(THREADS)
void router_main(const float* __restrict__ x, const float* __restrict__ Wp,
                 const float* __restrict__ Wg, const float* __restrict__ lnw_g,
                 const float* __restrict__ lnb_g, const float* __restrict__ temp_g,
                 float* __restrict__ out_rw, float* __restrict__ out_disp,
                 float* __restrict__ ws_part)
{
    __shared__ float smem[TM * LDW + H * LDW];
    float* xs  = smem;            // [TM][LDW]
    float* wsm = smem + TM * LDW; // [H][LDW]
    // post-phase aliases
    float* wg_s = wsm;            // [E][H] = 4096 floats (fits in H*LDW = 9216)
    float* lb_s = xs;             // [16]
    float* z_s  = xs + 16;        // [1]

    const int t   = threadIdx.x;
    const int tx  = t & 15;       // h-group / expert lane
    const int ty  = t >> 4;       // 0..31, owns tokens 2*ty, 2*ty+1
    const int tok0 = blockIdx.x * TM;

    float acc[2][16];
    #pragma unroll
    for (int i = 0; i < 2; ++i)
        #pragma unroll
        for (int j = 0; j < 16; ++j) acc[i][j] = 0.f;

    for (int k0 = 0; k0 < D; k0 += BK) {
        // stage x tile: 64 tokens x 32 k  (512 thr x 1 float4)
        {
            const int tok = t >> 3;
            const int c   = (t & 7) << 2;
            const float4 v = *(const float4*)&x[(size_t)(tok0 + tok) * D + k0 + c];
            *(float4*)&xs[tok * LDW + c] = v;
        }
        // stage Wp tile: 256 h x 32 k (4 passes)
        #pragma unroll
        for (int p = 0; p < 4; ++p) {
            const int r = p * 64 + (t >> 3);
            const int c = (t & 7) << 2;
            const float4 v = *(const float4*)&Wp[(size_t)r * D + k0 + c];
            *(float4*)&wsm[r * LDW + c] = v;
        }
        __syncthreads();
        #pragma unroll
        for (int kk = 0; kk < BK; kk += 4) {
            const float4 xa = *(const float4*)&xs[(2 * ty + 0) * LDW + kk];
            const float4 xb = *(const float4*)&xs[(2 * ty + 1) * LDW + kk];
            #pragma unroll
            for (int j = 0; j < 16; ++j) {
                const float4 w = *(const float4*)&wsm[(tx + 16 * j) * LDW + kk];
                acc[0][j] = fmaf(xa.x, w.x, acc[0][j]);
                acc[0][j] = fmaf(xa.y, w.y, acc[0][j]);
                acc[0][j] = fmaf(xa.z, w.z, acc[0][j]);
                acc[0][j] = fmaf(xa.w, w.w, acc[0][j]);
                acc[1][j] = fmaf(xb.x, w.x, acc[1][j]);
                acc[1][j] = fmaf(xb.y, w.y, acc[1][j]);
                acc[1][j] = fmaf(xb.z, w.z, acc[1][j]);
                acc[1][j] = fmaf(xb.w, w.w, acc[1][j]);
            }
        }
        __syncthreads();
    }

    // ---- post phase: stage Wg into LDS (alias over wsm), zero reducers ----
    #pragma unroll
    for (int p = 0; p < 2; ++p) {
        const int idx = p * 512 + t;   // 1024 float4s total
        *(float4*)&wg_s[idx * 4] = *(const float4*)&Wg[idx * 4];
    }
    if (t < 16) lb_s[t] = 0.f;
    if (t == 16) z_s[0] = 0.f;
    __syncthreads();

    float lnw[16], lnb[16];
    #pragma unroll
    for (int j = 0; j < 16; ++j) {
        lnw[j] = lnw_g[tx + 16 * j];
        lnb[j] = lnb_g[tx + 16 * j];
    }
    const float temp = fabsf(temp_g[0]) + 1e-6f;

    float mylb = 0.f;   // partial load for expert tx
    float myz  = 0.f;

    #pragma unroll
    for (int i = 0; i < 2; ++i) {
        const int tok = tok0 + 2 * ty + i;
        // mean over H
        float s = 0.f;
        #pragma unroll
        for (int j = 0; j < 16; ++j) s += acc[i][j];
        s += __shfl_xor(s, 1); s += __shfl_xor(s, 2);
        s += __shfl_xor(s, 4); s += __shfl_xor(s, 8);
        const float mu = s * (1.f / 256.f);
        // variance
        float v = 0.f;
        #pragma unroll
        for (int j = 0; j < 16; ++j) { const float d = acc[i][j] - mu; v = fmaf(d, d, v); }
        v += __shfl_xor(v, 1); v += __shfl_xor(v, 2);
        v += __shfl_xor(v, 4); v += __shfl_xor(v, 8);
        const float rstd = 1.0f / sqrtf(v * (1.f / 256.f) + 1e-5f);
        // normalized (strided h = tx + 16j)
        float n[16];
        #pragma unroll
        for (int j = 0; j < 16; ++j)
            n[j] = fmaf((acc[i][j] - mu) * rstd, lnw[j], lnb[j]);
        // logits partials over this lane's 16 h-columns
        float p[16];
        #pragma unroll
        for (int e = 0; e < 16; ++e) p[e] = 0.f;
        #pragma unroll
        for (int j = 0; j < 16; ++j) {
            const float nv = n[j];
            const int  h  = tx + 16 * j;
            #pragma unroll
            for (int e = 0; e < 16; ++e)
                p[e] = fmaf(nv, wg_s[e * H + h], p[e]);
        }
        // butterfly across the 16-lane group: full logits in every lane
        #pragma unroll
        for (int m = 1; m < 16; m <<= 1)
            #pragma unroll
            for (int e = 0; e < 16; ++e) p[e] += __shfl_xor(p[e], m);
        // temperature
        #pragma unroll
        for (int e = 0; e < 16; ++e) p[e] = p[e] / temp;
        // z-loss partial (one lane per token)
        if (tx == 0) {
            float z = 0.f;
            #pragma unroll
            for (int e = 0; e < 16; ++e) z = fmaf(p[e], p[e], z);
            myz += z;
        }
        // softmax (stable)
        float mx = p[0];
        #pragma unroll
        for (int e = 1; e < 16; ++e) mx = fmaxf(mx, p[e]);
        float w[16]; float sw = 0.f;
        #pragma unroll
        for (int e = 0; e < 16; ++e) { w[e] = expf(p[e] - mx); sw += w[e]; }
        #pragma unroll
        for (int e = 0; e < 16; ++e) w[e] = w[e] / sw;
        mylb += w[tx];
        // top-2 (ties -> lower index, matches lax.top_k)
        float w1 = -1.f; int i1 = 0; float w2 = -1.f; int i2 = 0;
        #pragma unroll
        for (int e = 0; e < 16; ++e) {
            const float we = w[e];
            if (we > w1)      { w2 = w1; i2 = i1; w1 = we; i1 = e; }
            else if (we > w2) { w2 = we; i2 = e; }
        }
        const float rs = 1.f / (w1 + w2 + 1e-6f);
        const float v1 = w1 * rs, v2 = w2 * rs;
        // outputs: lane tx writes element tx
        out_rw  [(size_t)tok * E + tx] = w[tx];
        out_disp[(size_t)tok * E + tx] = (tx == i1) ? v1 : (tx == i2 ? v2 : 0.f);
    }

    atomicAdd(&lb_s[tx], mylb);
    if (tx == 0) atomicAdd(&z_s[0], myz);
    __syncthreads();
    if (t < 16)  ws_part[blockIdx.x * WS_STRIDE + t]  = lb_s[t];
    if (t == 16) ws_part[blockIdx.x * WS_STRIDE + 16] = z_s[0];
}

__global__ void router_final(const float* __restrict__ ws_part,
                             float* __restrict__ out_loss, int nblocks, int T)
{
    const int l = threadIdx.x;   // 64 threads
    float lb[16]; float z = 0.f;
    #pragma unroll
    for (int e = 0; e < 16; ++e) lb[e] = 0.f;
    for (int b = l; b < nblocks; b += 64) {
        #pragma unroll
        for (int e = 0; e < 16; ++e) lb[e] += ws_part[b * WS_STRIDE + e];
        z += ws_part[b * WS_STRIDE + 16];
    }
    #pragma unroll
    for (int m = 1; m < 64; m <<= 1) {
        #pragma unroll
        for (int e = 0; e < 16; ++e) lb[e] += __shfl_xor(lb[e], m);
        z += __shfl_xor(z, m);
    }
    if (l == 0) {
        const float zloss = z / (float)(T * 16);
        const float ideal = 1.f / 16.f;
        float lbl = 0.f;
        #pragma unroll
        for (int e = 0; e < 16; ++e) {
            const float a = lb[e] / (float)T;
            lbl += ideal * (logf(ideal) - logf(a));
        }
        lbl *= (1.f / 16.f);
        out_loss[0] = 0.005f * zloss + 0.005f * lbl;
    }
}

extern "C" void kernel_launch(void* const* d_in, const int* in_sizes, int n_in,
                              void* d_out, int out_size, void* d_ws, size_t ws_size,
                              hipStream_t stream)
{
    const float* x    = (const float*)d_in[0];
    const float* Wp   = (const float*)d_in[1];
    const float* Wg   = (const float*)d_in[2];
    const float* lnw  = (const float*)d_in[3];
    const float* lnb  = (const float*)d_in[4];
    const float* temp = (const float*)d_in[5];
    const int T = in_sizes[0] / D;           // 16384
    float* out      = (float*)d_out;
    float* out_rw   = out;
    float* out_disp = out + (size_t)T * E;
    float* out_loss = out + (size_t)2 * T * E;
    float* ws_part  = (float*)d_ws;
    const int nblocks = T / TM;              // 256

    hipLaunchKernelGGL(router_main, dim3(nblocks), dim3(THREADS), 0, stream,
                       x, Wp, Wg, lnw, lnb, temp, out_rw, out_disp, ws_part);
    hipLaunchKernelGGL(router_final, dim3(1), dim3(64), 0, stream,
                       ws_part, out_loss, nblocks, T);
}